// Round 4
// baseline (132.929 us; speedup 1.0000x reference)
//
#include <hip/hip_runtime.h>
#include <cstddef>

#define L1n 128
#define L2n 256
#define Kn  1024

using frag_ab = __attribute__((ext_vector_type(8))) short;  // 8 bf16
using frag_cd = __attribute__((ext_vector_type(4))) float;  // 4 f32

// RNE f32->bf16 pair pack (low, high)
__device__ __forceinline__ unsigned pack_bf16(float x, float y) {
    unsigned ux = __float_as_uint(x);
    ux = (ux + 0x7FFFu + ((ux >> 16) & 1u)) >> 16;
    unsigned uy = __float_as_uint(y);
    uy = (uy + 0x7FFFu + ((uy >> 16) & 1u)) & 0xFFFF0000u;
    return ux | uy;
}

// ---------------- Kernel 1: fused row-norm + bf16-MFMA GEMM + dist ----------------
// grid = 512 blocks, 512 threads (8 waves). K-split: waves 0-3 do K[0,512),
// waves 4-7 do K[512,1024) into separate LDS buffers -> 16 waves/CU.
// Operand-swapped MFMA (mfma(b,a)) yields C^T in-register, so the transposed
// dist_t[b][col][row] store is coalesced dword stores (64B segments).
__global__ __launch_bounds__(512, 4) void gemm_dist_kernel(
    const float* __restrict__ seq1,
    const float* __restrict__ seq2,
    float* __restrict__ dist)
{
    __shared__ __align__(16) unsigned char sA[2][2][8192];  // [grp][dbuf][64 rows x 128 B]
    __shared__ __align__(16) unsigned char sB[2][2][8192];
    __shared__ float sSS[2][2][64];                          // [grp][A/B][row]
    __shared__ float sInvA[64];
    __shared__ float sInvB[64];

    // bijective XCD-chunk swizzle (512 % 8 == 0): one batch's 8 blocks share an XCD
    const int wg   = ((blockIdx.x & 7) << 6) + (blockIdx.x >> 3);
    const int b    = wg >> 3;
    const int mt   = (wg >> 2) & 1;
    const int nt   = wg & 3;
    const int t    = threadIdx.x;
    const int lane = t & 63;
    const int w    = t >> 6;          // 0..7
    const int grp  = w >> 2;          // K-half group
    const int wr   = (w >> 1) & 1;
    const int wc   = w & 1;
    const int tl   = t & 255;
    const int r    = tl >> 2;         // staging row 0..63
    const int j    = tl & 3;          // staging chunk 0..3

    const float4* pA = reinterpret_cast<const float4*>(
        seq1 + (size_t)b * (L1n * Kn) + (size_t)(mt * 64 + r) * Kn) + grp * 128 + j;
    const float4* pB = reinterpret_cast<const float4*>(
        seq2 + (size_t)b * (L2n * Kn) + (size_t)(nt * 64 + r) * Kn) + grp * 128 + j;

    const int swz = (r & 7) << 4;

    float ssA = 0.0f, ssB = 0.0f;
    frag_cd acc[2][2] = {};   // [nj][mi] (operand-swapped)

    float4 av[4], bv[4];
#pragma unroll
    for (int i = 0; i < 4; ++i) { av[i] = pA[4 * i]; bv[i] = pB[4 * i]; }

#pragma unroll
    for (int i = 0; i < 4; ++i) {
        ssA += av[i].x * av[i].x + av[i].y * av[i].y + av[i].z * av[i].z + av[i].w * av[i].w;
        ssB += bv[i].x * bv[i].x + bv[i].y * bv[i].y + bv[i].z * bv[i].z + bv[i].w * bv[i].w;
        const int kb = (j + 4 * i) * 8;
        *reinterpret_cast<uint2*>(&sA[grp][0][r * 128 + (kb ^ swz)]) =
            make_uint2(pack_bf16(av[i].x, av[i].y), pack_bf16(av[i].z, av[i].w));
        *reinterpret_cast<uint2*>(&sB[grp][0][r * 128 + (kb ^ swz)]) =
            make_uint2(pack_bf16(bv[i].x, bv[i].y), pack_bf16(bv[i].z, bv[i].w));
    }

    for (int s = 0; s < 8; ++s) {
        __syncthreads();
        const int cur = s & 1;

        if (s + 1 < 8) {
#pragma unroll
            for (int i = 0; i < 4; ++i) {
                av[i] = pA[(s + 1) * 16 + 4 * i];
                bv[i] = pB[(s + 1) * 16 + 4 * i];
            }
        }

#pragma unroll
        for (int kk = 0; kk < 2; ++kk) {
            const int kb = kk * 64 + ((lane >> 4) << 4);
            const int m0 = wr * 32 + (lane & 15);
            const int n0 = wc * 32 + (lane & 15);
            const int fswz = ((lane & 7) << 4);
            frag_ab a0 = *reinterpret_cast<const frag_ab*>(&sA[grp][cur][m0 * 128 + (kb ^ fswz)]);
            frag_ab a1 = *reinterpret_cast<const frag_ab*>(&sA[grp][cur][(m0 + 16) * 128 + (kb ^ fswz)]);
            frag_ab b0 = *reinterpret_cast<const frag_ab*>(&sB[grp][cur][n0 * 128 + (kb ^ fswz)]);
            frag_ab b1 = *reinterpret_cast<const frag_ab*>(&sB[grp][cur][(n0 + 16) * 128 + (kb ^ fswz)]);
            // operand-swapped: acc[nj][mi], reg-dim = seq2 col, lane&15 = seq1 row
            acc[0][0] = __builtin_amdgcn_mfma_f32_16x16x32_bf16(b0, a0, acc[0][0], 0, 0, 0);
            acc[0][1] = __builtin_amdgcn_mfma_f32_16x16x32_bf16(b0, a1, acc[0][1], 0, 0, 0);
            acc[1][0] = __builtin_amdgcn_mfma_f32_16x16x32_bf16(b1, a0, acc[1][0], 0, 0, 0);
            acc[1][1] = __builtin_amdgcn_mfma_f32_16x16x32_bf16(b1, a1, acc[1][1], 0, 0, 0);
        }

        if (s + 1 < 8) {
            const int nxt = cur ^ 1;
#pragma unroll
            for (int i = 0; i < 4; ++i) {
                ssA += av[i].x * av[i].x + av[i].y * av[i].y + av[i].z * av[i].z + av[i].w * av[i].w;
                ssB += bv[i].x * bv[i].x + bv[i].y * bv[i].y + bv[i].z * bv[i].z + bv[i].w * bv[i].w;
                const int kb = (j + 4 * i) * 8;
                *reinterpret_cast<uint2*>(&sA[grp][nxt][r * 128 + (kb ^ swz)]) =
                    make_uint2(pack_bf16(av[i].x, av[i].y), pack_bf16(av[i].z, av[i].w));
                *reinterpret_cast<uint2*>(&sB[grp][nxt][r * 128 + (kb ^ swz)]) =
                    make_uint2(pack_bf16(bv[i].x, bv[i].y), pack_bf16(bv[i].z, bv[i].w));
            }
        }
    }

    __syncthreads();   // all MFMA LDS reads done; buffers reusable

    // partial row sum-of-squares -> LDS; grp1 parks its acc in LDS (reuse sA region)
    ssA += __shfl_xor(ssA, 1); ssA += __shfl_xor(ssA, 2);
    ssB += __shfl_xor(ssB, 1); ssB += __shfl_xor(ssB, 2);
    if (j == 0) { sSS[grp][0][r] = ssA; sSS[grp][1][r] = ssB; }

    float* cmb = reinterpret_cast<float*>(sA);   // 64x65 f32 = 16.6 KB < 32 KB
    if (grp == 1) {
#pragma unroll
        for (int nj = 0; nj < 2; ++nj)
#pragma unroll
            for (int mi = 0; mi < 2; ++mi) {
                const int m_l = wr * 32 + mi * 16 + (lane & 15);
                const int n_b = wc * 32 + nj * 16 + ((lane >> 4) << 2);
#pragma unroll
                for (int reg = 0; reg < 4; ++reg)
                    cmb[(n_b + reg) * 65 + m_l] = acc[nj][mi][reg];
            }
    }
    __syncthreads();

    if (t < 64)       sInvA[t]      = rsqrtf(sSS[0][0][t] + sSS[1][0][t]);
    else if (t < 128) sInvB[t - 64] = rsqrtf(sSS[0][1][t - 64] + sSS[1][1][t - 64]);

    if (grp == 0) {
#pragma unroll
        for (int nj = 0; nj < 2; ++nj)
#pragma unroll
            for (int mi = 0; mi < 2; ++mi) {
                const int m_l = wr * 32 + mi * 16 + (lane & 15);
                const int n_b = wc * 32 + nj * 16 + ((lane >> 4) << 2);
#pragma unroll
                for (int reg = 0; reg < 4; ++reg)
                    acc[nj][mi][reg] += cmb[(n_b + reg) * 65 + m_l];
            }
    }
    __syncthreads();

    if (grp == 0) {
        float* dbase = dist + (size_t)b * (L1n * L2n);
#pragma unroll
        for (int nj = 0; nj < 2; ++nj)
#pragma unroll
            for (int mi = 0; mi < 2; ++mi) {
                const int m_l = wr * 32 + mi * 16 + (lane & 15);
                const int n_b = wc * 32 + nj * 16 + ((lane >> 4) << 2);
                const float ia = sInvA[m_l];
                const int grow = mt * 64 + m_l;
#pragma unroll
                for (int reg = 0; reg < 4; ++reg) {
                    const int n_l = n_b + reg;
                    dbase[(size_t)(nt * 64 + n_l) * L1n + grow] =
                        1.0f - acc[nj][mi][reg] * ia * sInvB[n_l];
                }
            }
    }
}

// ---------------- Kernel 2: DTW lag-skewed column sweep, global-direct ----------------
// Lane l owns rows 2l,2l+1; sweeps cols with LAG=4 skew. No LDS staging:
// dist is L2/L3-resident; 16-deep register prefetch hides load latency.
// INF-initialized carries make all column-boundary selects disappear:
// per-step carried chain = fmin+add (8 cy).
__global__ __launch_bounds__(64) void dtw_kernel(
    const float* __restrict__ dist, float* __restrict__ out)
{
    const int b    = blockIdx.x;
    const int lane = threadIdx.x;
    const float INF = 3.0e38f;
    const bool lane0 = (lane == 0);
    const float* base = dist + (size_t)b * (L1n * L2n) + 2 * lane;  // [col][row]

    float c0 = INF, c1 = INF;
    float sh0 = INF, sh1 = INF, sh2 = INF, sh3 = INF, sh4 = INF;

    auto ldval = [&](int tt) -> float2 {
        int jj = tt - 4 * lane;
        jj = jj < 0 ? 0 : (jj > L2n - 1 ? L2n - 1 : jj);
        return *reinterpret_cast<const float2*>(base + (size_t)jj * L1n);
    };

    auto step = [&](float2 d, bool t0) {
        float u = lane0 ? (t0 ? 0.0f : INF) : sh3;   // D(r0-1, jj)
        float g = lane0 ? INF : sh4;                  // D(r0-1, jj-1)
        float ugm = fminf(u, g);
        float n0 = d.x + fminf(c0, ugm);
        float n1 = d.y + fminf(fminf(c1, c0), n0);
        float snew = __shfl_up(n1, 1);
        sh4 = sh3; sh3 = sh2; sh2 = sh1; sh1 = sh0; sh0 = snew;
        c0 = n0; c1 = n1;
    };

    float2 pfA[8], pfB[8];
#pragma unroll
    for (int u = 0; u < 8; ++u) pfA[u] = ldval(u);
#pragma unroll
    for (int u = 0; u < 8; ++u) pfB[u] = ldval(8 + u);

    // peeled first block (t = 0..7), t==0 handles cell (0,0)
#pragma unroll
    for (int u = 0; u < 8; ++u) step(pfA[u], u == 0);
#pragma unroll
    for (int u = 0; u < 8; ++u) pfA[u] = ldval(16 + u);

    int t = 8;
    for (int i = 0; i < 31; ++i) {    // t = 8 .. 503
        float2 curB[8];
#pragma unroll
        for (int u = 0; u < 8; ++u) curB[u] = pfB[u];
#pragma unroll
        for (int u = 0; u < 8; ++u) pfB[u] = ldval(t + 16 + u);
#pragma unroll
        for (int u = 0; u < 8; ++u) step(curB[u], false);

        float2 curA[8];
#pragma unroll
        for (int u = 0; u < 8; ++u) curA[u] = pfA[u];
#pragma unroll
        for (int u = 0; u < 8; ++u) pfA[u] = ldval(t + 24 + u);
#pragma unroll
        for (int u = 0; u < 8; ++u) step(curA[u], false);
        t += 16;
    }

    // tail: t = 504..507 from pfB
#pragma unroll
    for (int u = 0; u < 4; ++u) step(pfB[u], false);

    // lane 63 finished (127,255) at t=507 -> c1
    if (lane == 63)
        out[b] = 1.0f / (1.0f + c1 * (1.0f / (float)(L1n + L2n)));
}

extern "C" void kernel_launch(void* const* d_in, const int* in_sizes, int n_in,
                              void* d_out, int out_size, void* d_ws, size_t ws_size,
                              hipStream_t stream) {
    const float* seq1 = (const float*)d_in[0];   // 64*128*1024 f32
    const float* seq2 = (const float*)d_in[1];   // 64*256*1024 f32
    float* out  = (float*)d_out;                 // 64 f32
    float* dist = (float*)d_ws;                  // 8 MB scratch (transposed dist)

    gemm_dist_kernel<<<dim3(512), dim3(512), 0, stream>>>(seq1, seq2, dist);
    dtw_kernel<<<dim3(64), dim3(64), 0, stream>>>(dist, out);
}

// Round 5
// 48.635 us; speedup vs baseline: 2.7332x; 2.7332x over previous
//
#include <hip/hip_runtime.h>
#include <cstddef>

#define L1n 128
#define L2n 256
#define Kn  1024

using frag_ab = __attribute__((ext_vector_type(8))) short;  // 8 bf16
using frag_cd = __attribute__((ext_vector_type(4))) float;  // 4 f32

// RNE f32->bf16 pair pack (low, high)
__device__ __forceinline__ unsigned pack_bf16(float x, float y) {
    unsigned ux = __float_as_uint(x);
    ux = (ux + 0x7FFFu + ((ux >> 16) & 1u)) >> 16;
    unsigned uy = __float_as_uint(y);
    uy = (uy + 0x7FFFu + ((uy >> 16) & 1u)) & 0xFFFF0000u;
    return ux | uy;
}

// ---------------- Kernel 1: fused row-norm + bf16-MFMA GEMM + dist ----------------
// grid = 512 blocks (2/CU), 256 threads (4 waves, 2x2). 64x64 tile, BK=64.
// 2-phase-deep register prefetch: data loaded at phase s is converted into
// LDS at phase s+1's tail and consumed at phase s+2 -> a full phase of
// latency-covering distance. Operand-swapped MFMA (mfma(b,a)) gives C^T
// in-register so the transposed dist_t[b][col][row] store is coalesced.
// NO min-wave launch bound: R4 showed (512,4) caps VGPR=64 -> 167MB scratch spill.
__global__ __launch_bounds__(256) void gemm_dist_kernel(
    const float* __restrict__ seq1,
    const float* __restrict__ seq2,
    float* __restrict__ dist)
{
    __shared__ __align__(16) unsigned char sA[2][8192];  // 64 rows x 128 B (64 bf16)
    __shared__ __align__(16) unsigned char sB[2][8192];
    __shared__ float sInvA[64];
    __shared__ float sInvB[64];

    // bijective XCD-chunk swizzle (512 % 8 == 0)
    const int wg   = ((blockIdx.x & 7) << 6) + (blockIdx.x >> 3);
    const int b    = wg >> 3;
    const int mt   = (wg >> 2) & 1;
    const int nt   = wg & 3;
    const int t    = threadIdx.x;
    const int lane = t & 63;
    const int w    = t >> 6;
    const int wr   = w >> 1;
    const int wc   = w & 1;
    const int r    = t >> 2;     // staging row 0..63
    const int j    = t & 3;      // staging chunk 0..3
    const int swz  = (r & 7) << 4;

    const float4* pA = reinterpret_cast<const float4*>(
        seq1 + (size_t)b * (L1n * Kn) + (size_t)(mt * 64 + r) * Kn) + j;
    const float4* pB = reinterpret_cast<const float4*>(
        seq2 + (size_t)b * (L2n * Kn) + (size_t)(nt * 64 + r) * Kn) + j;

    float ssA = 0.0f, ssB = 0.0f;
    frag_cd acc[2][2] = {};   // [nj][mi] (operand-swapped)

    float4 avA[4], bvA[4], avB[4], bvB[4];

    auto issue = [&](float4* av, float4* bv, int s) {
#pragma unroll
        for (int i = 0; i < 4; ++i) { av[i] = pA[s * 16 + 4 * i]; bv[i] = pB[s * 16 + 4 * i]; }
    };
    auto convert = [&](const float4* av, const float4* bv, int buf) {
#pragma unroll
        for (int i = 0; i < 4; ++i) {
            ssA += av[i].x * av[i].x + av[i].y * av[i].y + av[i].z * av[i].z + av[i].w * av[i].w;
            ssB += bv[i].x * bv[i].x + bv[i].y * bv[i].y + bv[i].z * bv[i].z + bv[i].w * bv[i].w;
            const int kb = (j + 4 * i) * 8;
            *reinterpret_cast<uint2*>(&sA[buf][r * 128 + (kb ^ swz)]) =
                make_uint2(pack_bf16(av[i].x, av[i].y), pack_bf16(av[i].z, av[i].w));
            *reinterpret_cast<uint2*>(&sB[buf][r * 128 + (kb ^ swz)]) =
                make_uint2(pack_bf16(bv[i].x, bv[i].y), pack_bf16(bv[i].z, bv[i].w));
        }
    };
    auto domfma = [&](int buf) {
#pragma unroll
        for (int kk = 0; kk < 2; ++kk) {
            const int kb = kk * 64 + ((lane >> 4) << 4);
            const int m0 = wr * 32 + (lane & 15);
            const int n0 = wc * 32 + (lane & 15);
            const int fswz = (lane & 7) << 4;   // rows m0,m0+16,n0,n0+16 all have (row&7)==(lane&7)
            frag_ab a0 = *reinterpret_cast<const frag_ab*>(&sA[buf][m0 * 128 + (kb ^ fswz)]);
            frag_ab a1 = *reinterpret_cast<const frag_ab*>(&sA[buf][(m0 + 16) * 128 + (kb ^ fswz)]);
            frag_ab b0 = *reinterpret_cast<const frag_ab*>(&sB[buf][n0 * 128 + (kb ^ fswz)]);
            frag_ab b1 = *reinterpret_cast<const frag_ab*>(&sB[buf][(n0 + 16) * 128 + (kb ^ fswz)]);
            // swapped: M-dim = seq2 cols (reg dim), N-dim = seq1 rows (lane&15)
            acc[0][0] = __builtin_amdgcn_mfma_f32_16x16x32_bf16(b0, a0, acc[0][0], 0, 0, 0);
            acc[0][1] = __builtin_amdgcn_mfma_f32_16x16x32_bf16(b0, a1, acc[0][1], 0, 0, 0);
            acc[1][0] = __builtin_amdgcn_mfma_f32_16x16x32_bf16(b1, a0, acc[1][0], 0, 0, 0);
            acc[1][1] = __builtin_amdgcn_mfma_f32_16x16x32_bf16(b1, a1, acc[1][1], 0, 0, 0);
        }
    };

    // prologue: step 0 -> buf0; step 1 pending in avA
    issue(avA, bvA, 0);
    convert(avA, bvA, 0);
    issue(avA, bvA, 1);

#pragma unroll
    for (int s = 0; s < 16; s += 2) {
        __syncthreads();
        if (s + 2 < 16) issue(avB, bvB, s + 2);   // consumed at phase s+1 tail
        domfma(0);
        convert(avA, bvA, 1);                      // data s+1 (loaded a full phase ago)

        __syncthreads();
        if (s + 3 < 16) issue(avA, bvA, s + 3);
        domfma(1);
        if (s + 2 < 16) convert(avB, bvB, 0);      // data s+2
    }

    // full-row sum of squares: threads 4r..4r+3 share row r (same wave)
    ssA += __shfl_xor(ssA, 1); ssA += __shfl_xor(ssA, 2);
    ssB += __shfl_xor(ssB, 1); ssB += __shfl_xor(ssB, 2);
    if (j == 0) { sInvA[r] = rsqrtf(ssA); sInvB[r] = rsqrtf(ssB); }
    __syncthreads();

    // epilogue: dist_t[b][col][row] = 1 - acc^T * invA * invB, coalesced stores
    float* dbase = dist + (size_t)b * (L1n * L2n);
#pragma unroll
    for (int nj = 0; nj < 2; ++nj)
#pragma unroll
        for (int mi = 0; mi < 2; ++mi) {
            const int m_l = wr * 32 + mi * 16 + (lane & 15);
            const int n_b = wc * 32 + nj * 16 + ((lane >> 4) << 2);
            const float ia = sInvA[m_l];
            const int grow = mt * 64 + m_l;
#pragma unroll
            for (int reg = 0; reg < 4; ++reg) {
                const int n_l = n_b + reg;
                dbase[(size_t)(nt * 64 + n_l) * L1n + grow] =
                    1.0f - acc[nj][mi][reg] * ia * sInvB[n_l];
            }
        }
}

// ---------------- Kernel 2: DTW lag-skewed column sweep, global-direct ----------------
// (measured ~2.4 us in R4 -- unchanged)
__global__ __launch_bounds__(64) void dtw_kernel(
    const float* __restrict__ dist, float* __restrict__ out)
{
    const int b    = blockIdx.x;
    const int lane = threadIdx.x;
    const float INF = 3.0e38f;
    const bool lane0 = (lane == 0);
    const float* base = dist + (size_t)b * (L1n * L2n) + 2 * lane;  // [col][row]

    float c0 = INF, c1 = INF;
    float sh0 = INF, sh1 = INF, sh2 = INF, sh3 = INF, sh4 = INF;

    auto ldval = [&](int tt) -> float2 {
        int jj = tt - 4 * lane;
        jj = jj < 0 ? 0 : (jj > L2n - 1 ? L2n - 1 : jj);
        return *reinterpret_cast<const float2*>(base + (size_t)jj * L1n);
    };

    auto step = [&](float2 d, bool t0) {
        float u = lane0 ? (t0 ? 0.0f : INF) : sh3;   // D(r0-1, jj)
        float g = lane0 ? INF : sh4;                  // D(r0-1, jj-1)
        float ugm = fminf(u, g);
        float n0 = d.x + fminf(c0, ugm);
        float n1 = d.y + fminf(fminf(c1, c0), n0);
        float snew = __shfl_up(n1, 1);
        sh4 = sh3; sh3 = sh2; sh2 = sh1; sh1 = sh0; sh0 = snew;
        c0 = n0; c1 = n1;
    };

    float2 pfA[8], pfB[8];
#pragma unroll
    for (int u = 0; u < 8; ++u) pfA[u] = ldval(u);
#pragma unroll
    for (int u = 0; u < 8; ++u) pfB[u] = ldval(8 + u);

#pragma unroll
    for (int u = 0; u < 8; ++u) step(pfA[u], u == 0);
#pragma unroll
    for (int u = 0; u < 8; ++u) pfA[u] = ldval(16 + u);

    int t = 8;
    for (int i = 0; i < 31; ++i) {    // t = 8 .. 503
        float2 curB[8];
#pragma unroll
        for (int u = 0; u < 8; ++u) curB[u] = pfB[u];
#pragma unroll
        for (int u = 0; u < 8; ++u) pfB[u] = ldval(t + 16 + u);
#pragma unroll
        for (int u = 0; u < 8; ++u) step(curB[u], false);

        float2 curA[8];
#pragma unroll
        for (int u = 0; u < 8; ++u) curA[u] = pfA[u];
#pragma unroll
        for (int u = 0; u < 8; ++u) pfA[u] = ldval(t + 24 + u);
#pragma unroll
        for (int u = 0; u < 8; ++u) step(curA[u], false);
        t += 16;
    }

#pragma unroll
    for (int u = 0; u < 4; ++u) step(pfB[u], false);

    if (lane == 63)
        out[b] = 1.0f / (1.0f + c1 * (1.0f / (float)(L1n + L2n)));
}

extern "C" void kernel_launch(void* const* d_in, const int* in_sizes, int n_in,
                              void* d_out, int out_size, void* d_ws, size_t ws_size,
                              hipStream_t stream) {
    const float* seq1 = (const float*)d_in[0];   // 64*128*1024 f32
    const float* seq2 = (const float*)d_in[1];   // 64*256*1024 f32
    float* out  = (float*)d_out;                 // 64 f32
    float* dist = (float*)d_ws;                  // 8 MB scratch (transposed dist)

    gemm_dist_kernel<<<dim3(512), dim3(256), 0, stream>>>(seq1, seq2, dist);
    dtw_kernel<<<dim3(64), dim3(64), 0, stream>>>(dist, out);
}